// Round 1
// baseline (253.058 us; speedup 1.0000x reference)
//
#include <hip/hip_runtime.h>
#include <hip/hip_bf16.h>

// FinDiffNonUniform: out[n,b] = sum_{s<7} coef[n,s] * y[n + off[n,s], b]
// N=8192, B=4096, S=7, fp32. Memory-bound (AI ~1.75 FLOP/B).
// One thread per float4 of output: 16B/lane coalesced loads+stores.
// Stencil coefficients/offsets are blockIdx-uniform -> scalar loads.

#define FD_N 8192
#define FD_B 4096
#define FD_S 7

__global__ __launch_bounds__(256) void
_FinDiffNonUniform_51608327029442_kernel(const float* __restrict__ y,
                                         const float* __restrict__ coef,
                                         const int*   __restrict__ offs,
                                         float*       __restrict__ out) {
    // 4 chunks of 1024 floats per row; 256 threads x float4 per chunk.
    const int chunk = blockIdx.x;
    const int n     = chunk >> 2;                       // row index
    const int b     = ((chunk & 3) << 10) + (threadIdx.x << 2);

    // Uniform (per-block) stencil data -> scalar loads.
    float c[FD_S];
    int   o[FD_S];
#pragma unroll
    for (int s = 0; s < FD_S; ++s) {
        c[s] = coef[n * FD_S + s];
        o[s] = offs[n * FD_S + s];
    }

    float4 acc = make_float4(0.f, 0.f, 0.f, 0.f);
#pragma unroll
    for (int s = 0; s < FD_S; ++s) {
        const size_t idx = (size_t)(n + o[s]) * FD_B + b;
        const float4 v = *reinterpret_cast<const float4*>(y + idx);
        acc.x += c[s] * v.x;
        acc.y += c[s] * v.y;
        acc.z += c[s] * v.z;
        acc.w += c[s] * v.w;
    }

    *reinterpret_cast<float4*>(out + (size_t)n * FD_B + b) = acc;
}

extern "C" void kernel_launch(void* const* d_in, const int* in_sizes, int n_in,
                              void* d_out, int out_size, void* d_ws, size_t ws_size,
                              hipStream_t stream) {
    const float* y    = (const float*)d_in[0];
    const float* coef = (const float*)d_in[1];
    const int*   offs = (const int*)d_in[2];
    float*       out  = (float*)d_out;

    // N*(B/1024) blocks, 256 threads each; each thread writes one float4.
    const int blocks = FD_N * (FD_B / 1024);
    _FinDiffNonUniform_51608327029442_kernel<<<blocks, 256, 0, stream>>>(y, coef, offs, out);
}

// Round 2
// 236.002 us; speedup vs baseline: 1.0723x; 1.0723x over previous
//
#include <hip/hip_runtime.h>
#include <hip/hip_bf16.h>

// FinDiffNonUniform: out[n,b] = sum_{s<7} coef[n,s] * y[n + off[n,s], b]
// N=8192, B=4096, S=7, fp32.
// Register-blocked over n: each thread owns one float4 column and R=8
// consecutive rows; loads a sliding window of R+6 rows once (read
// amplification 7x -> 1.75x through the cache hierarchy, which was the
// round-1 limiter at ~11 TB/s aggregate). Interior rows use the centered
// [-3..3] stencil (exact by _make_offsets construction); boundary strips
// use the generic gather path with the actual offsets.

#define FD_N 8192
#define FD_B 4096
#define FD_S 7
#define FD_R 8
#define HALO 3
#define WIN  (FD_R + 2 * HALO)   // 14

__global__ __launch_bounds__(256) void
_FinDiffNonUniform_51608327029442_kernel(const float* __restrict__ y,
                                         const float* __restrict__ coef,
                                         const int*   __restrict__ offs,
                                         float*       __restrict__ out) {
    const int strip = blockIdx.x >> 2;                   // n-strip of 8 rows
    const int n0    = strip * FD_R;
    const int b     = ((blockIdx.x & 3) << 10) + (threadIdx.x << 2);

    if (strip > 0 && strip < (FD_N / FD_R - 1)) {
        // ---- interior fast path: centered stencil, sliding register window
        float4 w[WIN];
        const float* ybase = y + (size_t)(n0 - HALO) * FD_B + b;
#pragma unroll
        for (int j = 0; j < WIN; ++j)
            w[j] = *reinterpret_cast<const float4*>(ybase + (size_t)j * FD_B);

#pragma unroll
        for (int r = 0; r < FD_R; ++r) {
            const float* cr = coef + (size_t)(n0 + r) * FD_S;  // block-uniform
            float4 acc = make_float4(0.f, 0.f, 0.f, 0.f);
#pragma unroll
            for (int s = 0; s < FD_S; ++s) {
                const float c = cr[s];
                acc.x += c * w[r + s].x;
                acc.y += c * w[r + s].y;
                acc.z += c * w[r + s].z;
                acc.w += c * w[r + s].w;
            }
            *reinterpret_cast<float4*>(out + (size_t)(n0 + r) * FD_B + b) = acc;
        }
    } else {
        // ---- boundary strips (first/last): generic gather with real offsets
#pragma unroll
        for (int r = 0; r < FD_R; ++r) {
            const int n = n0 + r;
            float4 acc = make_float4(0.f, 0.f, 0.f, 0.f);
#pragma unroll
            for (int s = 0; s < FD_S; ++s) {
                const float c = coef[n * FD_S + s];      // block-uniform
                const int   o = offs[n * FD_S + s];
                const float4 v =
                    *reinterpret_cast<const float4*>(y + (size_t)(n + o) * FD_B + b);
                acc.x += c * v.x;
                acc.y += c * v.y;
                acc.z += c * v.z;
                acc.w += c * v.w;
            }
            *reinterpret_cast<float4*>(out + (size_t)n * FD_B + b) = acc;
        }
    }
}

extern "C" void kernel_launch(void* const* d_in, const int* in_sizes, int n_in,
                              void* d_out, int out_size, void* d_ws, size_t ws_size,
                              hipStream_t stream) {
    const float* y    = (const float*)d_in[0];
    const float* coef = (const float*)d_in[1];
    const int*   offs = (const int*)d_in[2];
    float*       out  = (float*)d_out;

    // (N/8 strips) x (4 column chunks of 1024 floats), 256 threads/block.
    const int blocks = (FD_N / FD_R) * (FD_B / 1024);
    _FinDiffNonUniform_51608327029442_kernel<<<blocks, 256, 0, stream>>>(y, coef, offs, out);
}

// Round 3
// 235.561 us; speedup vs baseline: 1.0743x; 1.0019x over previous
//
#include <hip/hip_runtime.h>
#include <hip/hip_bf16.h>

// FinDiffNonUniform: out[n,b] = sum_{s<7} coef[n,s] * y[n + off[n,s], b]
// N=8192, B=4096, S=7, fp32.
//
// Round-2 lesson: at VGPR=36 the compiler serialized the 14-row register
// window into load->waitcnt->consume chains (latency-bound, 3 TB/s, no pipe
// saturated). This version forces MLP: __launch_bounds__(256,1) frees the
// allocator, all 14 window loads are issued back-to-back, and rows are
// consumed IN ARRIVAL ORDER (row j feeds acc[r] for r in [j-6, j]), giving
// the compiler a natural vmcnt(13..0) software pipeline.

#define FD_N 8192
#define FD_B 4096
#define FD_S 7
#define FD_R 8
#define HALO 3
#define WIN  (FD_R + 2 * HALO)   // 14

__global__ __launch_bounds__(256, 1) void
_FinDiffNonUniform_51608327029442_kernel(const float* __restrict__ y,
                                         const float* __restrict__ coef,
                                         const int*   __restrict__ offs,
                                         float*       __restrict__ out) {
    const int strip = blockIdx.x >> 2;                   // n-strip of 8 rows
    const int n0    = strip * FD_R;
    const int b     = ((blockIdx.x & 3) << 10) + (threadIdx.x << 2);

    if (strip > 0 && strip < (FD_N / FD_R - 1)) {
        // ---- interior fast path: centered [-3..3] stencil ----
        const float* ybase = y + (size_t)(n0 - HALO) * FD_B + b;

        // Issue all 14 row loads back-to-back (independent -> max MLP).
        float4 w[WIN];
#pragma unroll
        for (int j = 0; j < WIN; ++j)
            w[j] = *reinterpret_cast<const float4*>(ybase + (size_t)j * FD_B);

        // Block-uniform coefficients -> scalar loads (hoisted).
        float c[FD_R][FD_S];
#pragma unroll
        for (int r = 0; r < FD_R; ++r)
#pragma unroll
            for (int s = 0; s < FD_S; ++s)
                c[r][s] = coef[(size_t)(n0 + r) * FD_S + s];

        float4 acc[FD_R];
#pragma unroll
        for (int r = 0; r < FD_R; ++r)
            acc[r] = make_float4(0.f, 0.f, 0.f, 0.f);

        // Consume rows in arrival order: row j (= global row n0-3+j)
        // contributes to output r with stencil index s = j - r, s in [0,7).
#pragma unroll
        for (int j = 0; j < WIN; ++j) {
#pragma unroll
            for (int r = 0; r < FD_R; ++r) {
                const int s = j - r;
                if (s >= 0 && s < FD_S) {
                    const float cc = c[r][s];
                    acc[r].x += cc * w[j].x;
                    acc[r].y += cc * w[j].y;
                    acc[r].z += cc * w[j].z;
                    acc[r].w += cc * w[j].w;
                }
            }
        }

#pragma unroll
        for (int r = 0; r < FD_R; ++r)
            *reinterpret_cast<float4*>(out + (size_t)(n0 + r) * FD_B + b) = acc[r];
    } else {
        // ---- boundary strips (first/last): generic gather with real offsets
#pragma unroll
        for (int r = 0; r < FD_R; ++r) {
            const int n = n0 + r;
            float4 acc = make_float4(0.f, 0.f, 0.f, 0.f);
#pragma unroll
            for (int s = 0; s < FD_S; ++s) {
                const float cc = coef[n * FD_S + s];     // block-uniform
                const int   o  = offs[n * FD_S + s];
                const float4 v =
                    *reinterpret_cast<const float4*>(y + (size_t)(n + o) * FD_B + b);
                acc.x += cc * v.x;
                acc.y += cc * v.y;
                acc.z += cc * v.z;
                acc.w += cc * v.w;
            }
            *reinterpret_cast<float4*>(out + (size_t)n * FD_B + b) = acc;
        }
    }
}

extern "C" void kernel_launch(void* const* d_in, const int* in_sizes, int n_in,
                              void* d_out, int out_size, void* d_ws, size_t ws_size,
                              hipStream_t stream) {
    const float* y    = (const float*)d_in[0];
    const float* coef = (const float*)d_in[1];
    const int*   offs = (const int*)d_in[2];
    float*       out  = (float*)d_out;

    // (N/8 strips) x (4 column chunks of 1024 floats), 256 threads/block.
    const int blocks = (FD_N / FD_R) * (FD_B / 1024);
    _FinDiffNonUniform_51608327029442_kernel<<<blocks, 256, 0, stream>>>(y, coef, offs, out);
}